// Round 2
// baseline (217.383 us; speedup 1.0000x reference)
//
#include <hip/hip_runtime.h>
#include <hip/hip_bf16.h>

#define NN 8192
#define IN_F 256
#define OF 128

typedef __bf16 bf16x8 __attribute__((ext_vector_type(8)));
typedef float  f32x4  __attribute__((ext_vector_type(4)));
typedef int    int4v  __attribute__((ext_vector_type(4)));

__device__ __forceinline__ int4v nt_load4(const int* p) {
    return __builtin_nontemporal_load((const int4v*)p);
}

// ---------------------------------------------------------------------------
// Kernel A: h = X @ W (f32, LDS-staged W); emit Ht (bf16, transposed [OF][NN]),
// f_src = h.a[:OF], f_dst = h.a[OF:].  Unchanged from R1 (~3 us).
// ---------------------------------------------------------------------------
__global__ __launch_bounds__(256) void gat_prep(
    const float* __restrict__ X, const float* __restrict__ W,
    const float* __restrict__ a, __bf16* __restrict__ Ht,
    float* __restrict__ f_src, float* __restrict__ f_dst)
{
    __shared__ float Wlds[IN_F * OF];   // 128 KiB
    __shared__ float red_s[32][8];
    __shared__ float red_d[32][8];

    const int t = threadIdx.x;
    {
        const f32x4* Wv = (const f32x4*)W;
        f32x4*       Wl = (f32x4*)Wlds;
        #pragma unroll
        for (int c = 0; c < 32; ++c) Wl[c * 256 + t] = Wv[c * 256 + t];
    }
    __syncthreads();

    const int row = t & 31;
    const int sub = t >> 5;
    const int i   = blockIdx.x * 32 + row;

    f32x4 acc[4] = {};
    const float* xrow = X + (size_t)i * IN_F;

    #pragma unroll 4
    for (int kk = 0; kk < IN_F; kk += 4) {
        f32x4 xv = *(const f32x4*)(xrow + kk);
        #pragma unroll
        for (int e = 0; e < 4; ++e) {
            const f32x4* wr = (const f32x4*)(Wlds + (kk + e) * OF + sub * 16);
            float xs = xv[e];
            #pragma unroll
            for (int c4 = 0; c4 < 4; ++c4) acc[c4] += xs * wr[c4];
        }
    }

    float ps = 0.f, pd = 0.f;
    #pragma unroll
    for (int c4 = 0; c4 < 4; ++c4) {
        #pragma unroll
        for (int e = 0; e < 4; ++e) {
            float v = acc[c4][e];
            int   c = sub * 16 + c4 * 4 + e;
            ps += v * a[c];
            pd += v * a[OF + c];
            Ht[(size_t)c * NN + i] = (__bf16)v;
        }
    }
    red_s[row][sub] = ps;
    red_d[row][sub] = pd;
    __syncthreads();
    if (t < 32) {
        float s = 0.f;
        #pragma unroll
        for (int s8 = 0; s8 < 8; ++s8) s += red_s[t][s8];
        f_src[blockIdx.x * 32 + t] = s;
    } else if (t < 64) {
        const int r2 = t - 32;
        float s = 0.f;
        #pragma unroll
        for (int s8 = 0; s8 < 8; ++s8) s += red_d[r2][s8];
        f_dst[blockIdx.x * 32 + r2] = s;
    }
}

// ---------------------------------------------------------------------------
// Kernel B v2: flash-GAT, latency-optimized.
// 512 blocks x 512 threads (8 waves), 16 rows/block, waves split j 8-ways.
// Changes vs R1:
//  - bf[8] register staging: all 8 Ht fragments outstanding before MFMAs
//  - adj prefetched 1 iteration ahead (issued AFTER bf loads so the counted
//    vmcnt wait for bf leaves the prefetch in flight across the MFMAs)
//  - nontemporal adj loads (don't evict Ht from L2)
//  - LDS tree reduction: 32 KiB instead of 64 KiB
// ---------------------------------------------------------------------------
__global__ __launch_bounds__(512) void gat_flash(
    const int* __restrict__ adj, const __bf16* __restrict__ Ht,
    const float* __restrict__ f_src, const float* __restrict__ f_dst,
    float* __restrict__ out)
{
    __shared__ float red[4][16][OF];   // 32 KiB
    __shared__ float rden[8][16];

    const int tid  = threadIdx.x;
    const int wave = tid >> 6;
    const int lane = tid & 63;
    const int r    = lane & 15;
    const int g    = lane >> 4;
    const int rowbase = blockIdx.x * 16;
    const int i    = rowbase + r;

    const float fsrc_i = f_src[i];
    const int* adjrow  = adj + (size_t)i * NN;

    f32x4 acc[8] = {};
    float psum = 0.f;

    // prime the adj prefetch
    int4v a0 = nt_load4(adjrow + wave * 32 + g * 8);
    int4v a1 = nt_load4(adjrow + wave * 32 + g * 8 + 4);

    for (int tile = wave; tile < NN / 32; tile += 8) {
        const int kbase = tile * 32 + g * 8;

        // f_dst (L1/L2-resident, 32 KB total)
        const f32x4 fd0 = *(const f32x4*)(f_dst + kbase);
        const f32x4 fd1 = *(const f32x4*)(f_dst + kbase + 4);

        // stage all 8 B-fragments (L2-resident Ht) into registers
        bf16x8 bf[8];
        #pragma unroll
        for (int nt = 0; nt < 8; ++nt)
            bf[nt] = *(const bf16x8*)(Ht + (size_t)(nt * 16 + r) * NN + kbase);

        // prefetch NEXT tile's adj (youngest loads -> stay in flight)
        const int ptile = (tile + 8 < NN / 32) ? tile + 8 : tile;
        const int pkbase = ptile * 32 + g * 8;
        int4v na0 = nt_load4(adjrow + pkbase);
        int4v na1 = nt_load4(adjrow + pkbase + 4);

        const int   av[8]  = {a0.x, a0.y, a0.z, a0.w, a1.x, a1.y, a1.z, a1.w};
        const float fdv[8] = {fd0[0], fd0[1], fd0[2], fd0[3],
                              fd1[0], fd1[1], fd1[2], fd1[3]};
        float p[8];
        bf16x8 af;
        #pragma unroll
        for (int e = 0; e < 8; ++e) {
            float s = fsrc_i + fdv[e];
            s = s > 0.f ? s : 0.2f * s;          // leaky_relu
            float pe = (av[e] != 0) ? __expf(s) : 0.f;
            p[e] = pe;
            af[e] = (__bf16)pe;
        }
        psum += ((p[0] + p[1]) + (p[2] + p[3])) + ((p[4] + p[5]) + (p[6] + p[7]));

        #pragma unroll
        for (int nt = 0; nt < 8; ++nt)
            acc[nt] = __builtin_amdgcn_mfma_f32_16x16x32_bf16(af, bf[nt], acc[nt], 0, 0, 0);

        a0 = na0; a1 = na1;
    }

    // reduce psum over the 4 k-groups
    psum += __shfl_xor(psum, 16, 64);
    psum += __shfl_xor(psum, 32, 64);
    if (lane < 16) rden[wave][lane] = psum;

    // tree reduction across waves: 4-7 write, 0-3 add
    if (wave >= 4) {
        #pragma unroll
        for (int nt = 0; nt < 8; ++nt)
            #pragma unroll
            for (int q = 0; q < 4; ++q)
                red[wave - 4][g * 4 + q][nt * 16 + r] = acc[nt][q];
    }
    __syncthreads();
    if (wave < 4) {
        #pragma unroll
        for (int nt = 0; nt < 8; ++nt)
            #pragma unroll
            for (int q = 0; q < 4; ++q)
                red[wave][g * 4 + q][nt * 16 + r] += acc[nt][q];
    }
    __syncthreads();

    // epilogue: 512 threads x 1 f32x4 = 16x128 tile
    const int orow = tid >> 5;     // 0..15
    const int cg   = tid & 31;     // 4-col group
    f32x4 v = {};
    #pragma unroll
    for (int w = 0; w < 4; ++w)
        v += *(const f32x4*)&red[w][orow][cg * 4];
    float den = 0.f;
    #pragma unroll
    for (int w = 0; w < 8; ++w) den += rden[w][orow];
    const float inv = 1.0f / den;
    f32x4 o = v * inv;
    #pragma unroll
    for (int e = 0; e < 4; ++e) o[e] = fmaxf(o[e], 0.f);
    *(f32x4*)(out + (size_t)(rowbase + orow) * OF + cg * 4) = o;
}

extern "C" void kernel_launch(void* const* d_in, const int* in_sizes, int n_in,
                              void* d_out, int out_size, void* d_ws, size_t ws_size,
                              hipStream_t stream) {
    const float* X   = (const float*)d_in[0];
    const int*   adj = (const int*)d_in[1];
    const float* W   = (const float*)d_in[2];
    const float* a   = (const float*)d_in[3];
    float* out = (float*)d_out;

    __bf16* Ht    = (__bf16*)d_ws;                                  // 2 MiB
    float*  f_src = (float*)((char*)d_ws + (size_t)OF * NN * sizeof(__bf16));
    float*  f_dst = f_src + NN;

    gat_prep<<<NN / 32, 256, 0, stream>>>(X, W, a, Ht, f_src, f_dst);
    gat_flash<<<NN / 16, 512, 0, stream>>>(adj, Ht, f_src, f_dst, out);
}

// Round 3
// 165.773 us; speedup vs baseline: 1.3113x; 1.3113x over previous
//
#include <hip/hip_runtime.h>
#include <hip/hip_bf16.h>

#define NN 8192
#define IN_F 256
#define OF 128

typedef float  f32x4   __attribute__((ext_vector_type(4)));
typedef short  short4v __attribute__((ext_vector_type(4)));
typedef short  short8v __attribute__((ext_vector_type(8)));
typedef int    int4v   __attribute__((ext_vector_type(4)));

__device__ __forceinline__ int4v nt_load4(const int* p) {
    return __builtin_nontemporal_load((const int4v*)p);
}

__device__ __forceinline__ unsigned short bf16_bits(float x) {
    __bf16 b = (__bf16)x;
    return __builtin_bit_cast(unsigned short, b);
}

__device__ __forceinline__ f32x4 mfma16(short4v a, short4v b, f32x4 c) {
#if __has_builtin(__builtin_amdgcn_mfma_f32_16x16x16bf16_1k)
    return __builtin_amdgcn_mfma_f32_16x16x16bf16_1k(a, b, c, 0, 0, 0);
#else
    asm("v_mfma_f32_16x16x16_bf16 %0, %1, %2, %0" : "+v"(c) : "v"(a), "v"(b));
    return c;
#endif
}

// ---------------------------------------------------------------------------
// Kernel A: h = X @ W (f32, LDS-staged W).
// Emits HtB in MFMA-B-fragment order:
//   HtB element index for h[j][f]:
//     tile=j>>4, g=(j>>2)&3, e=j&3, np=f>>5... (np = (f>>4)>>1), o=(f>>4)&1, c=f&15
//     idx = ((tile*4+np)*64 + g*16 + c)*8 + o*4 + e
// so gat_flash loads one 16B (short8v) per lane = two B fragments, 1KB/inst
// fully contiguous.  Also f_src = h.a[:OF], f_dst = h.a[OF:].
// ---------------------------------------------------------------------------
__global__ __launch_bounds__(256) void gat_prep(
    const float* __restrict__ X, const float* __restrict__ W,
    const float* __restrict__ a, unsigned short* __restrict__ HtB,
    float* __restrict__ f_src, float* __restrict__ f_dst)
{
    __shared__ float Wlds[IN_F * OF];   // 128 KiB
    __shared__ float red_s[32][8];
    __shared__ float red_d[32][8];

    const int t = threadIdx.x;
    {
        const f32x4* Wv = (const f32x4*)W;
        f32x4*       Wl = (f32x4*)Wlds;
        #pragma unroll
        for (int c = 0; c < 32; ++c) Wl[c * 256 + t] = Wv[c * 256 + t];
    }
    __syncthreads();

    const int row = t & 31;
    const int sub = t >> 5;       // feature block nt = sub (16 features)
    const int i   = blockIdx.x * 32 + row;

    f32x4 acc[4] = {};
    const float* xrow = X + (size_t)i * IN_F;

    #pragma unroll 4
    for (int kk = 0; kk < IN_F; kk += 4) {
        f32x4 xv = *(const f32x4*)(xrow + kk);
        #pragma unroll
        for (int e = 0; e < 4; ++e) {
            const f32x4* wr = (const f32x4*)(Wlds + (kk + e) * OF + sub * 16);
            float xs = xv[e];
            #pragma unroll
            for (int c4 = 0; c4 < 4; ++c4) acc[c4] += xs * wr[c4];
        }
    }

    const int tile = i >> 4;
    const int gq   = (i >> 2) & 3;
    const int eq   = i & 3;
    const int np   = sub >> 1;
    const int oo   = sub & 1;

    float ps = 0.f, pd = 0.f;
    #pragma unroll
    for (int c4 = 0; c4 < 4; ++c4) {
        #pragma unroll
        for (int e = 0; e < 4; ++e) {
            float v = acc[c4][e];
            int   c = c4 * 4 + e;                 // 0..15 within feature block
            ps += v * a[sub * 16 + c];
            pd += v * a[OF + sub * 16 + c];
            HtB[(size_t)(((tile * 4 + np) * 64) + gq * 16 + c) * 8 + oo * 4 + eq]
                = bf16_bits(v);
        }
    }
    red_s[row][sub] = ps;
    red_d[row][sub] = pd;
    __syncthreads();
    if (t < 32) {
        float s = 0.f;
        #pragma unroll
        for (int s8 = 0; s8 < 8; ++s8) s += red_s[t][s8];
        f_src[blockIdx.x * 32 + t] = s;
    } else if (t < 64) {
        const int r2 = t - 32;
        float s = 0.f;
        #pragma unroll
        for (int s8 = 0; s8 < 8; ++s8) s += red_d[r2][s8];
        f_dst[blockIdx.x * 32 + r2] = s;
    }
}

// ---------------------------------------------------------------------------
// Kernel B v3: flash-GAT with line-perfect loads.
// 512 blocks x 512 threads (8 waves), 16 rows/block, waves stride j-tiles by 8.
// MFMA 16x16x16 bf16, K=16 per tile:
//   A: row=lane&15 (adj row), k=4*(lane>>4)+e  -> one int4/lane, each adj row
//      is one fully-used 64B line per instruction.
//   B: col=lane&15, k=4*(lane>>4)+e -> HtB fragment-packed, 1KB contiguous/inst.
//   D: col=lane&15, row=4*(lane>>4)+q.
// Depth-2 pipeline on adj/f_dst: consumed value was loaded 2 iters ago.
// ---------------------------------------------------------------------------
__global__ __launch_bounds__(512) void gat_flash(
    const int* __restrict__ adj, const unsigned short* __restrict__ HtB,
    const float* __restrict__ f_src, const float* __restrict__ f_dst,
    float* __restrict__ out)
{
    __shared__ float red[4][16][OF];   // 32 KiB
    __shared__ float rden[8][16];

    const int tid  = threadIdx.x;
    const int wave = tid >> 6;
    const int lane = tid & 63;
    const int r    = lane & 15;
    const int g    = lane >> 4;
    const int rowbase = blockIdx.x * 16;

    const float fsrc_r = f_src[rowbase + r];
    const int*   aptr = adj + (size_t)(rowbase + r) * NN + g * 4;
    const float* fptr = f_dst + g * 4;
    const short8v* htv = (const short8v*)HtB;

    f32x4 acc[8] = {};
    float psum = 0.f;

    // depth-2 pipeline on adj + f_dst
    int4v pa0 = nt_load4(aptr + wave * 16);
    int4v pa1 = nt_load4(aptr + (wave + 8) * 16);
    f32x4 pf0 = *(const f32x4*)(fptr + wave * 16);
    f32x4 pf1 = *(const f32x4*)(fptr + (wave + 8) * 16);

    for (int it = 0; it < 64; ++it) {
        const int tile = wave + it * 8;

        // B fragments: 4 x 1KB contiguous loads (2 fragments each)
        short8v bp0 = htv[(size_t)(tile * 4 + 0) * 64 + lane];
        short8v bp1 = htv[(size_t)(tile * 4 + 1) * 64 + lane];
        short8v bp2 = htv[(size_t)(tile * 4 + 2) * 64 + lane];
        short8v bp3 = htv[(size_t)(tile * 4 + 3) * 64 + lane];

        // rotate pipeline; issue prefetch for it+2
        const int4v a_cur = pa0; const f32x4 f_cur = pf0;
        pa0 = pa1; pf0 = pf1;
        const int pt = (it + 2 < 64) ? (tile + 16) : tile;
        pa1 = nt_load4(aptr + pt * 16);
        pf1 = *(const f32x4*)(fptr + pt * 16);

        float p[4];
        #pragma unroll
        for (int e = 0; e < 4; ++e) {
            float s = fsrc_r + f_cur[e];
            s = s > 0.f ? s : 0.2f * s;              // leaky_relu
            p[e] = (a_cur[e] != 0) ? __expf(s) : 0.f;
        }
        psum += (p[0] + p[1]) + (p[2] + p[3]);
        short4v af = { (short)bf16_bits(p[0]), (short)bf16_bits(p[1]),
                       (short)bf16_bits(p[2]), (short)bf16_bits(p[3]) };

        short4v b0l = __builtin_shufflevector(bp0, bp0, 0, 1, 2, 3);
        short4v b0h = __builtin_shufflevector(bp0, bp0, 4, 5, 6, 7);
        short4v b1l = __builtin_shufflevector(bp1, bp1, 0, 1, 2, 3);
        short4v b1h = __builtin_shufflevector(bp1, bp1, 4, 5, 6, 7);
        short4v b2l = __builtin_shufflevector(bp2, bp2, 0, 1, 2, 3);
        short4v b2h = __builtin_shufflevector(bp2, bp2, 4, 5, 6, 7);
        short4v b3l = __builtin_shufflevector(bp3, bp3, 0, 1, 2, 3);
        short4v b3h = __builtin_shufflevector(bp3, bp3, 4, 5, 6, 7);

        acc[0] = mfma16(af, b0l, acc[0]);
        acc[1] = mfma16(af, b0h, acc[1]);
        acc[2] = mfma16(af, b1l, acc[2]);
        acc[3] = mfma16(af, b1h, acc[3]);
        acc[4] = mfma16(af, b2l, acc[4]);
        acc[5] = mfma16(af, b2h, acc[5]);
        acc[6] = mfma16(af, b3l, acc[6]);
        acc[7] = mfma16(af, b3h, acc[7]);
    }

    // denom: reduce psum over the 4 k-groups (lanes with same r)
    psum += __shfl_xor(psum, 16, 64);
    psum += __shfl_xor(psum, 32, 64);
    if (lane < 16) rden[wave][lane] = psum;

    // tree reduction across waves: 4-7 write, 0-3 add
    if (wave >= 4) {
        #pragma unroll
        for (int nt = 0; nt < 8; ++nt)
            #pragma unroll
            for (int q = 0; q < 4; ++q)
                red[wave - 4][g * 4 + q][nt * 16 + r] = acc[nt][q];
    }
    __syncthreads();
    if (wave < 4) {
        #pragma unroll
        for (int nt = 0; nt < 8; ++nt)
            #pragma unroll
            for (int q = 0; q < 4; ++q)
                red[wave][g * 4 + q][nt * 16 + r] += acc[nt][q];
    }
    __syncthreads();

    // epilogue: 512 threads x 1 f32x4 = 16x128 tile
    const int orow = tid >> 5;
    const int cg   = tid & 31;
    f32x4 v = {};
    #pragma unroll
    for (int w = 0; w < 4; ++w)
        v += *(const f32x4*)&red[w][orow][cg * 4];
    float den = 0.f;
    #pragma unroll
    for (int w = 0; w < 8; ++w) den += rden[w][orow];
    const float inv = 1.0f / den;
    f32x4 o = v * inv;
    #pragma unroll
    for (int e = 0; e < 4; ++e) o[e] = fmaxf(o[e], 0.f);
    *(f32x4*)(out + (size_t)(rowbase + orow) * OF + cg * 4) = o;
}

extern "C" void kernel_launch(void* const* d_in, const int* in_sizes, int n_in,
                              void* d_out, int out_size, void* d_ws, size_t ws_size,
                              hipStream_t stream) {
    const float* X   = (const float*)d_in[0];
    const int*   adj = (const int*)d_in[1];
    const float* W   = (const float*)d_in[2];
    const float* a   = (const float*)d_in[3];
    float* out = (float*)d_out;

    unsigned short* HtB = (unsigned short*)d_ws;                    // 2 MiB
    float* f_src = (float*)((char*)d_ws + (size_t)OF * NN * sizeof(unsigned short));
    float* f_dst = f_src + NN;

    gat_prep<<<NN / 32, 256, 0, stream>>>(X, W, a, HtB, f_src, f_dst);
    gat_flash<<<NN / 16, 512, 0, stream>>>(adj, HtB, f_src, f_dst, out);
}

// Round 4
// 164.127 us; speedup vs baseline: 1.3245x; 1.0100x over previous
//
#include <hip/hip_runtime.h>
#include <hip/hip_bf16.h>

#define NN 8192
#define IN_F 256
#define OF 128

typedef float  f32x4   __attribute__((ext_vector_type(4)));
typedef short  short4v __attribute__((ext_vector_type(4)));
typedef short  short8v __attribute__((ext_vector_type(8)));
typedef int    int4v   __attribute__((ext_vector_type(4)));

__device__ __forceinline__ int4v nt_load4(const int* p) {
    return __builtin_nontemporal_load((const int4v*)p);
}

__device__ __forceinline__ unsigned short bf16_bits(float x) {
    __bf16 b = (__bf16)x;
    return __builtin_bit_cast(unsigned short, b);
}

__device__ __forceinline__ f32x4 mfma16(short4v a, short4v b, f32x4 c) {
#if __has_builtin(__builtin_amdgcn_mfma_f32_16x16x16bf16_1k)
    return __builtin_amdgcn_mfma_f32_16x16x16bf16_1k(a, b, c, 0, 0, 0);
#else
    asm("v_mfma_f32_16x16x16_bf16 %0, %1, %2, %0" : "+v"(c) : "v"(a), "v"(b));
    return c;
#endif
}

// ---------------------------------------------------------------------------
// Kernel A: h = X @ W (f32, LDS-staged W).  Emits HtB in MFMA-B-fragment
// order (verified R3):  for h[j][f]:
//   tile=j>>4, g=(j>>2)&3, e=j&3, np=f>>5, o=(f>>4)&1, c=f&15
//   idx = ((tile*4+np)*64 + g*16 + c)*8 + o*4 + e
// Also f_src = h.a[:OF], f_dst = h.a[OF:].
// ---------------------------------------------------------------------------
__global__ __launch_bounds__(256) void gat_prep(
    const float* __restrict__ X, const float* __restrict__ W,
    const float* __restrict__ a, unsigned short* __restrict__ HtB,
    float* __restrict__ f_src, float* __restrict__ f_dst)
{
    __shared__ float Wlds[IN_F * OF];   // 128 KiB
    __shared__ float red_s[32][8];
    __shared__ float red_d[32][8];

    const int t = threadIdx.x;
    {
        const f32x4* Wv = (const f32x4*)W;
        f32x4*       Wl = (f32x4*)Wlds;
        #pragma unroll
        for (int c = 0; c < 32; ++c) Wl[c * 256 + t] = Wv[c * 256 + t];
    }
    __syncthreads();

    const int row = t & 31;
    const int sub = t >> 5;
    const int i   = blockIdx.x * 32 + row;

    f32x4 acc[4] = {};
    const float* xrow = X + (size_t)i * IN_F;

    #pragma unroll 4
    for (int kk = 0; kk < IN_F; kk += 4) {
        f32x4 xv = *(const f32x4*)(xrow + kk);
        #pragma unroll
        for (int e = 0; e < 4; ++e) {
            const f32x4* wr = (const f32x4*)(Wlds + (kk + e) * OF + sub * 16);
            float xs = xv[e];
            #pragma unroll
            for (int c4 = 0; c4 < 4; ++c4) acc[c4] += xs * wr[c4];
        }
    }

    const int tile = i >> 4;
    const int gq   = (i >> 2) & 3;
    const int eq   = i & 3;
    const int np   = sub >> 1;
    const int oo   = sub & 1;

    float ps = 0.f, pd = 0.f;
    #pragma unroll
    for (int c4 = 0; c4 < 4; ++c4) {
        #pragma unroll
        for (int e = 0; e < 4; ++e) {
            float v = acc[c4][e];
            int   c = c4 * 4 + e;
            ps += v * a[sub * 16 + c];
            pd += v * a[OF + sub * 16 + c];
            HtB[(size_t)(((tile * 4 + np) * 64) + gq * 16 + c) * 8 + oo * 4 + eq]
                = bf16_bits(v);
        }
    }
    red_s[row][sub] = ps;
    red_d[row][sub] = pd;
    __syncthreads();
    if (t < 32) {
        float s = 0.f;
        #pragma unroll
        for (int s8 = 0; s8 < 8; ++s8) s += red_s[t][s8];
        f_src[blockIdx.x * 32 + t] = s;
    } else if (t < 64) {
        const int r2 = t - 32;
        float s = 0.f;
        #pragma unroll
        for (int s8 = 0; s8 < 8; ++s8) s += red_d[r2][s8];
        f_dst[blockIdx.x * 32 + r2] = s;
    }
}

// ---------------------------------------------------------------------------
// Kernel B v4: flash-GAT, fully register-pipelined.
//  - HtB fragments: depth-1 explicit prefetch (named hb0..3 / nb0..3 rotation)
//    -> the waitcnt before the MFMA cluster waits only on loads issued one
//    full iteration earlier; young loads stay in flight (counted vmcnt).
//  - adj: depth-3 queue (HBM latency ~900cy), nontemporal.
//  - f_dst: depth-3 queue (cheap).
// ---------------------------------------------------------------------------
__global__ __launch_bounds__(512) void gat_flash(
    const int* __restrict__ adj, const unsigned short* __restrict__ HtB,
    const float* __restrict__ f_src, const float* __restrict__ f_dst,
    float* __restrict__ out)
{
    __shared__ float red[4][16][OF];   // 32 KiB
    __shared__ float rden[8][16];

    const int tid  = threadIdx.x;
    const int wave = tid >> 6;
    const int lane = tid & 63;
    const int r    = lane & 15;
    const int g    = lane >> 4;
    const int rowbase = blockIdx.x * 16;

    const float fsrc_r = f_src[rowbase + r];
    const int*   aptr = adj + (size_t)(rowbase + r) * NN + g * 4;
    const float* fptr = f_dst + g * 4;
    const short8v* htv = (const short8v*)HtB;

    f32x4 acc[8] = {};
    float psum = 0.f;

    // ---- prologue: prime pipelines ----
    // HtB for it=0
    short8v hb0 = htv[(size_t)(wave * 4 + 0) * 64 + lane];
    short8v hb1 = htv[(size_t)(wave * 4 + 1) * 64 + lane];
    short8v hb2 = htv[(size_t)(wave * 4 + 2) * 64 + lane];
    short8v hb3 = htv[(size_t)(wave * 4 + 3) * 64 + lane];
    // adj/f_dst for it=0,1,2
    int4v a0 = nt_load4(aptr + (wave +  0) * 16);
    int4v a1 = nt_load4(aptr + (wave +  8) * 16);
    int4v a2 = nt_load4(aptr + (wave + 16) * 16);
    f32x4 f0 = *(const f32x4*)(fptr + (wave +  0) * 16);
    f32x4 f1 = *(const f32x4*)(fptr + (wave +  8) * 16);
    f32x4 f2 = *(const f32x4*)(fptr + (wave + 16) * 16);

    #pragma unroll 4
    for (int it = 0; it < 64; ++it) {
        const int tile = wave + it * 8;

        // issue next iteration's HtB loads (depth-1)
        const int ntile = (it + 1 < 64) ? tile + 8 : tile;
        short8v nb0 = htv[(size_t)(ntile * 4 + 0) * 64 + lane];
        short8v nb1 = htv[(size_t)(ntile * 4 + 1) * 64 + lane];
        short8v nb2 = htv[(size_t)(ntile * 4 + 2) * 64 + lane];
        short8v nb3 = htv[(size_t)(ntile * 4 + 3) * 64 + lane];

        // issue adj/f_dst for it+3 (depth-3)
        const int ptile = (it + 3 < 64) ? tile + 24 : tile;
        int4v na = nt_load4(aptr + ptile * 16);
        f32x4 nf = *(const f32x4*)(fptr + ptile * 16);

        // compute with a0/f0/hb* (all loaded >=1 iteration ago)
        float p[4];
        #pragma unroll
        for (int e = 0; e < 4; ++e) {
            float s = fsrc_r + f0[e];
            s = s > 0.f ? s : 0.2f * s;              // leaky_relu
            p[e] = (a0[e] != 0) ? __expf(s) : 0.f;
        }
        psum += (p[0] + p[1]) + (p[2] + p[3]);
        short4v af = { (short)bf16_bits(p[0]), (short)bf16_bits(p[1]),
                       (short)bf16_bits(p[2]), (short)bf16_bits(p[3]) };

        acc[0] = mfma16(af, __builtin_shufflevector(hb0, hb0, 0, 1, 2, 3), acc[0]);
        acc[1] = mfma16(af, __builtin_shufflevector(hb0, hb0, 4, 5, 6, 7), acc[1]);
        acc[2] = mfma16(af, __builtin_shufflevector(hb1, hb1, 0, 1, 2, 3), acc[2]);
        acc[3] = mfma16(af, __builtin_shufflevector(hb1, hb1, 4, 5, 6, 7), acc[3]);
        acc[4] = mfma16(af, __builtin_shufflevector(hb2, hb2, 0, 1, 2, 3), acc[4]);
        acc[5] = mfma16(af, __builtin_shufflevector(hb2, hb2, 4, 5, 6, 7), acc[5]);
        acc[6] = mfma16(af, __builtin_shufflevector(hb3, hb3, 0, 1, 2, 3), acc[6]);
        acc[7] = mfma16(af, __builtin_shufflevector(hb3, hb3, 4, 5, 6, 7), acc[7]);

        // rotate pipelines
        hb0 = nb0; hb1 = nb1; hb2 = nb2; hb3 = nb3;
        a0 = a1; a1 = a2; a2 = na;
        f0 = f1; f1 = f2; f2 = nf;
    }

    // denom: reduce psum over the 4 k-groups
    psum += __shfl_xor(psum, 16, 64);
    psum += __shfl_xor(psum, 32, 64);
    if (lane < 16) rden[wave][lane] = psum;

    // tree reduction across waves: 4-7 write, 0-3 add
    if (wave >= 4) {
        #pragma unroll
        for (int nt = 0; nt < 8; ++nt)
            #pragma unroll
            for (int q = 0; q < 4; ++q)
                red[wave - 4][g * 4 + q][nt * 16 + r] = acc[nt][q];
    }
    __syncthreads();
    if (wave < 4) {
        #pragma unroll
        for (int nt = 0; nt < 8; ++nt)
            #pragma unroll
            for (int q = 0; q < 4; ++q)
                red[wave][g * 4 + q][nt * 16 + r] += acc[nt][q];
    }
    __syncthreads();

    // epilogue: 512 threads x 1 f32x4 = 16x128 tile
    const int orow = tid >> 5;
    const int cg   = tid & 31;
    f32x4 v = {};
    #pragma unroll
    for (int w = 0; w < 4; ++w)
        v += *(const f32x4*)&red[w][orow][cg * 4];
    float den = 0.f;
    #pragma unroll
    for (int w = 0; w < 8; ++w) den += rden[w][orow];
    const float inv = 1.0f / den;
    f32x4 o = v * inv;
    #pragma unroll
    for (int e = 0; e < 4; ++e) o[e] = fmaxf(o[e], 0.f);
    *(f32x4*)(out + (size_t)(rowbase + orow) * OF + cg * 4) = o;
}

extern "C" void kernel_launch(void* const* d_in, const int* in_sizes, int n_in,
                              void* d_out, int out_size, void* d_ws, size_t ws_size,
                              hipStream_t stream) {
    const float* X   = (const float*)d_in[0];
    const int*   adj = (const int*)d_in[1];
    const float* W   = (const float*)d_in[2];
    const float* a   = (const float*)d_in[3];
    float* out = (float*)d_out;

    unsigned short* HtB = (unsigned short*)d_ws;                    // 2 MiB
    float* f_src = (float*)((char*)d_ws + (size_t)OF * NN * sizeof(unsigned short));
    float* f_dst = f_src + NN;

    gat_prep<<<NN / 32, 256, 0, stream>>>(X, W, a, HtB, f_src, f_dst);
    gat_flash<<<NN / 16, 512, 0, stream>>>(adj, HtB, f_src, f_dst, out);
}